// Round 6
// baseline (348.395 us; speedup 1.0000x reference)
//
#include <hip/hip_runtime.h>
#include <hip/hip_bf16.h>
#include <stdint.h>

typedef __hip_bfloat16 bf16s;                                    // storage type
typedef __bf16 bf16x8 __attribute__((ext_vector_type(8)));       // MFMA operand (4 VGPR)
typedef float  floatx16 __attribute__((ext_vector_type(16)));    // 32x32 MFMA acc

#define BM 256
#define BN 256
#define BK 64

__device__ __forceinline__ void gload_lds16(const void* g, void* l) {
    auto* gp = reinterpret_cast<const __attribute__((address_space(1))) uint32_t*>(
        reinterpret_cast<uintptr_t>(g));
    auto* lp = reinterpret_cast<__attribute__((address_space(3))) uint32_t*>(
        reinterpret_cast<uintptr_t>(l));
    __builtin_amdgcn_global_load_lds(gp, lp, 16, 0, 0);
}

// ---------- x (f32) -> bf16, vectorized ----------
__global__ void cvt_f32_bf16(const float* __restrict__ x, bf16s* __restrict__ y, long n4) {
    long i = (long)blockIdx.x * blockDim.x + threadIdx.x;
    long stride = (long)gridDim.x * blockDim.x;
    for (; i < n4; i += stride) {
        float4 v = ((const float4*)x)[i];
        bf16s tmp[4];
        tmp[0] = __float2bfloat16(v.x);
        tmp[1] = __float2bfloat16(v.y);
        tmp[2] = __float2bfloat16(v.z);
        tmp[3] = __float2bfloat16(v.w);
        *(uint2*)&y[i * 4] = *(uint2*)tmp;
    }
}

// ---------- Wadj = W + lora_B @ lora_A, output bf16 ----------
__global__ void adjust_weight(const float* __restrict__ W, const float* __restrict__ lA,
                              const float* __restrict__ lB, bf16s* __restrict__ Wb,
                              int N, int Kd, int r) {
    long idx = (long)blockIdx.x * blockDim.x + threadIdx.x;
    int kq = Kd >> 2;
    long total = (long)N * kq;
    if (idx >= total) return;
    int n  = (int)(idx / kq);
    int k4 = (int)(idx - (long)n * kq) << 2;
    float4 w = *(const float4*)&W[(size_t)n * Kd + k4];
    float a0 = w.x, a1 = w.y, a2 = w.z, a3 = w.w;
    for (int j = 0; j < r; ++j) {
        float b = lB[n * r + j];
        float4 av = *(const float4*)&lA[(size_t)j * Kd + k4];
        a0 += b * av.x; a1 += b * av.y; a2 += b * av.z; a3 += b * av.w;
    }
    bf16s tmp[4];
    tmp[0] = __float2bfloat16(a0);
    tmp[1] = __float2bfloat16(a1);
    tmp[2] = __float2bfloat16(a2);
    tmp[3] = __float2bfloat16(a3);
    *(uint2*)&Wb[(size_t)n * Kd + k4] = *(uint2*)tmp;
}

// ==========================================================================
// 256x256 tile, BK=64, 8 waves (2M x 4N), 32x32x16 MFMA, THREE phases/K-tile:
//   Ph1: stage ALL 8 gload_lds for t+1 | read a0(8),b0(4) | 8 MFMA (q00)
//   Ph2: read b1(4) | 8 MFMA (q01)
//   Ph3: read a1(8) | 16 MFMA (q11 + q10, reuses b0/b1 regs)
// One barrier per phase (3/K-tile vs 8 before). Deep vmcnt ledger:
//   end-Ph1 vmcnt(10) -> B1(t);  end-Ph2 vmcnt(8) -> A1(t);
//   end-Ph3 vmcnt(4)  -> A0,B0(t+1).   (stage order A0',B0',B1',A1')
// Invariant: {B1,A1}=4 loads outstanding entering each Ph1. Uniform clamped
// tail keeps counts exact; final vmcnt(0) drains DMA before s_endpgm.
// LDS slot s of row l holds source granule s ^ (l&7) (0-conflict measured).
// ==========================================================================
__global__ __launch_bounds__(512, 2)
void gemm_3phase(const bf16s* __restrict__ A,   // [M,K] bf16
                 const bf16s* __restrict__ B,   // [N,K] bf16
                 const float* __restrict__ bias,
                 float* __restrict__ C,         // [M,N] f32
                 int M, int N, int K) {
    __shared__ __align__(16) bf16s lds[2][2][BM * BK];   // [dbuf][A=0/B=1]

    const int nbn = N / BN;
    const int nwg = gridDim.x;
    int bid = blockIdx.x;
    int swz = bid;
    if ((nwg & 7) == 0) swz = (bid & 7) * (nwg >> 3) + (bid >> 3);   // XCD swizzle
    const int bm = swz / nbn, bn = swz % nbn;

    const int th   = threadIdx.x;
    const int lane = th & 63;
    const int wid  = th >> 6;
    const int wm = wid >> 2;           // 0..1 -> 128-row slice
    const int wn = wid & 3;            // 0..3 -> 64-col slice
    const int l31 = lane & 31;
    const int l5  = lane >> 5;         // 0..1: k-granule within frag

    const bf16s* gA = A + (size_t)(bm * BM) * K;
    const bf16s* gB = B + (size_t)(bn * BN) * K;
    const int NT = K / BK;

    floatx16 acc[2][2][2];             // [mh][nh][mp]  (32x32 frags)
#pragma unroll
    for (int i = 0; i < 2; ++i)
#pragma unroll
        for (int j = 0; j < 2; ++j)
#pragma unroll
            for (int p = 0; p < 2; ++p)
#pragma unroll
                for (int q = 0; q < 16; ++q)
                    acc[i][j][p][q] = 0.f;

    // ---- staging (identical to proven r4 layout): half-tile = 128 LDS rows,
    // 2 gload_lds per thread; slot s of row l holds source granule s^(l&7).
    const int trow = th >> 3;                       // 0..63 rows per G-load
    const int tgr  = (th & 7) ^ (trow & 7);         // pre-swizzled src granule

    auto stageA = [&](int dbuf, int mh, int k0) {
#pragma unroll
        for (int g = 0; g < 2; ++g) {
            int p = g * 128 + mh * 64 + trow;       // phys A row
            gload_lds16(gA + (size_t)p * K + k0 + tgr * 8,
                        &lds[dbuf][0][(mh * 128 + g * 64) * BK + th * 8]);
        }
    };
    auto stageB = [&](int dbuf, int nh, int k0) {
#pragma unroll
        for (int g = 0; g < 2; ++g) {
            int rest = g * 64 + trow;               // 0..127
            int p = (rest >> 5) * 64 + nh * 32 + (rest & 31);   // phys B row
            gload_lds16(gB + (size_t)p * K + k0 + tgr * 8,
                        &lds[dbuf][1][(nh * 128 + g * 64) * BK + th * 8]);
        }
    };

    // ---- 32x32 fragment reads (swizzled; l&7 == lane&7 in both cases) ----
    // A-frag: row = lane&31, k = kk*16 + (lane>>5)*8 + [0..7]
    auto ldA32 = [&](const bf16s* base, int mh, int mp, int kk) -> bf16x8 {
        int l = mh * 128 + wm * 64 + mp * 32 + l31;
        int c = ((kk << 1) | l5) ^ (lane & 7);
        return *(const bf16x8*)(base + l * BK + c * 8);
    };
    auto ldB32 = [&](const bf16s* base, int nh, int kk) -> bf16x8 {
        int l = nh * 128 + wn * 32 + l31;
        int c = ((kk << 1) | l5) ^ (lane & 7);
        return *(const bf16x8*)(base + l * BK + c * 8);
    };

    // ---- prologue: stage tile 0 (order A0,B0,B1,A1); publish A0,B0 ----
    stageA(0, 0, 0);
    stageB(0, 0, 0);
    stageB(0, 1, 0);
    stageA(0, 1, 0);
    asm volatile("s_waitcnt vmcnt(4)" ::: "memory");
    asm volatile("s_barrier" ::: "memory");

    for (int t = 0; t < NT; ++t) {
        const bf16s* Ab = &lds[t & 1][0][0];
        const bf16s* Bb = &lds[t & 1][1][0];
        const int nb = (t + 1) & 1;
        const int k1 = ((t + 1 < NT) ? (t + 1) : (NT - 1)) * BK;   // uniform tail

        bf16x8 a0[2][4], a1[2][4], b0[4], b1[4];

        // ============ Ph1: stage all of t+1; compute q(mh0,nh0) ============
        stageA(nb, 0, k1);          // A0'
        stageB(nb, 0, k1);          // B0'
        stageB(nb, 1, k1);          // B1'
        stageA(nb, 1, k1);          // A1'
#pragma unroll
        for (int kk = 0; kk < 4; ++kk)
            b0[kk] = ldB32(Bb, 0, kk);
#pragma unroll
        for (int mp = 0; mp < 2; ++mp)
#pragma unroll
            for (int kk = 0; kk < 4; ++kk)
                a0[mp][kk] = ldA32(Ab, 0, mp, kk);
        __builtin_amdgcn_s_setprio(1);
#pragma unroll
        for (int mp = 0; mp < 2; ++mp)
#pragma unroll
            for (int kk = 0; kk < 4; ++kk)
                acc[0][0][mp] = __builtin_amdgcn_mfma_f32_32x32x16_bf16(
                    a0[mp][kk], b0[kk], acc[0][0][mp], 0, 0, 0);
        __builtin_amdgcn_s_setprio(0);
        asm volatile("s_waitcnt vmcnt(10)" ::: "memory");   // B1(t) landed
        asm volatile("s_barrier" ::: "memory");

        // ============ Ph2: compute q(mh0,nh1) ============
#pragma unroll
        for (int kk = 0; kk < 4; ++kk)
            b1[kk] = ldB32(Bb, 1, kk);
        __builtin_amdgcn_s_setprio(1);
#pragma unroll
        for (int mp = 0; mp < 2; ++mp)
#pragma unroll
            for (int kk = 0; kk < 4; ++kk)
                acc[0][1][mp] = __builtin_amdgcn_mfma_f32_32x32x16_bf16(
                    a0[mp][kk], b1[kk], acc[0][1][mp], 0, 0, 0);
        __builtin_amdgcn_s_setprio(0);
        asm volatile("s_waitcnt vmcnt(8)" ::: "memory");    // A1(t) landed
        asm volatile("s_barrier" ::: "memory");

        // ============ Ph3: compute q(mh1,nh1) + q(mh1,nh0) ============
#pragma unroll
        for (int mp = 0; mp < 2; ++mp)
#pragma unroll
            for (int kk = 0; kk < 4; ++kk)
                a1[mp][kk] = ldA32(Ab, 1, mp, kk);
        __builtin_amdgcn_s_setprio(1);
#pragma unroll
        for (int mp = 0; mp < 2; ++mp)
#pragma unroll
            for (int kk = 0; kk < 4; ++kk)
                acc[1][1][mp] = __builtin_amdgcn_mfma_f32_32x32x16_bf16(
                    a1[mp][kk], b1[kk], acc[1][1][mp], 0, 0, 0);
#pragma unroll
        for (int mp = 0; mp < 2; ++mp)
#pragma unroll
            for (int kk = 0; kk < 4; ++kk)
                acc[1][0][mp] = __builtin_amdgcn_mfma_f32_32x32x16_bf16(
                    a1[mp][kk], b0[kk], acc[1][0][mp], 0, 0, 0);
        __builtin_amdgcn_s_setprio(0);
        asm volatile("s_waitcnt vmcnt(4)" ::: "memory");    // A0,B0(t+1) landed
        asm volatile("s_barrier" ::: "memory");
    }

    // drain our own outstanding LDS-DMA before s_endpgm
    asm volatile("s_waitcnt vmcnt(0)" ::: "memory");

    // ---- epilogue: 32x32 C/D layout (m74/m101):
    //   col = lane&31, row = (reg&3) + 8*(reg>>2) + 4*(lane>>5)
    const int crow = bm * BM + wm * 128;
    const int ccol = bn * BN + wn * 64;
#pragma unroll
    for (int nh = 0; nh < 2; ++nh) {
        int col = ccol + nh * 32 + l31;
        float bv = bias[col];
#pragma unroll
        for (int mh = 0; mh < 2; ++mh)
#pragma unroll
            for (int mp = 0; mp < 2; ++mp) {
                int rbase = crow + mh * 64 + mp * 32 + 4 * l5;
#pragma unroll
                for (int reg = 0; reg < 16; ++reg) {
                    int row = rbase + (reg & 3) + 8 * (reg >> 2);
                    C[(size_t)row * N + col] = acc[mh][nh][mp][reg] + bv;
                }
            }
    }
}

// ---------- fallback (f32, slow but correct) ----------
__global__ void xa_kernel(const float* __restrict__ x, const float* __restrict__ lA,
                          float* __restrict__ xa, long M, int K, int r) {
    long idx = (long)blockIdx.x * blockDim.x + threadIdx.x;
    long total = M * r;
    if (idx >= total) return;
    long m = idx / r; int j = (int)(idx % r);
    const float* xr = x + m * (long)K;
    const float* ar = lA + (size_t)j * K;
    float s = 0.f;
    for (int k = 0; k < K; k += 4) {
        float4 xv = *(const float4*)&xr[k];
        float4 av = *(const float4*)&ar[k];
        s += xv.x * av.x + xv.y * av.y + xv.z * av.z + xv.w * av.w;
    }
    xa[idx] = s;
}

__global__ void naive_out(const float* __restrict__ x, const float* __restrict__ W,
                          const float* __restrict__ bias, const float* __restrict__ xa,
                          const float* __restrict__ lB, float* __restrict__ out,
                          long M, int N, int K, int r) {
    long idx = (long)blockIdx.x * blockDim.x + threadIdx.x;
    long total = M * (long)N;
    if (idx >= total) return;
    long m = idx / N; int n = (int)(idx % N);
    const float* xr = x + m * (long)K;
    const float* wr = W + (size_t)n * K;
    float s = bias[n];
    for (int k = 0; k < K; k += 4) {
        float4 xv = *(const float4*)&xr[k];
        float4 wv = *(const float4*)&wr[k];
        s += xv.x * wv.x + xv.y * wv.y + xv.z * wv.z + xv.w * wv.w;
    }
    const float* xar = xa + m * r;
    const float* br  = lB + (size_t)n * r;
    for (int j = 0; j < r; ++j) s += xar[j] * br[j];
    out[idx] = s;
}

extern "C" void kernel_launch(void* const* d_in, const int* in_sizes, int n_in,
                              void* d_out, int out_size, void* d_ws, size_t ws_size,
                              hipStream_t stream) {
    const float* x    = (const float*)d_in[0];
    const float* W    = (const float*)d_in[1];
    const float* bias = (const float*)d_in[2];
    const float* lA   = (const float*)d_in[3];
    const float* lB   = (const float*)d_in[4];
    float* out = (float*)d_out;

    const int  N  = in_sizes[2];                  // d_out = 4096
    const int  Kd = in_sizes[1] / N;              // d_in  = 4096
    const int  r  = in_sizes[4] / N;              // 16
    const long M  = (long)in_sizes[0] / Kd;       // B*S   = 8192

    size_t xb_bytes = (size_t)M * Kd * sizeof(bf16s);
    size_t wb_bytes = (size_t)N * Kd * sizeof(bf16s);

    if (ws_size >= xb_bytes + wb_bytes &&
        (M % BM) == 0 && (N % BN) == 0 && (Kd % BK) == 0 && (Kd / BK) >= 2) {
        bf16s* xb = (bf16s*)d_ws;
        bf16s* wb = (bf16s*)((char*)d_ws + xb_bytes);

        long n4 = (long)M * Kd / 4;
        cvt_f32_bf16<<<2048, 256, 0, stream>>>(x, xb, n4);

        long total_w = (long)N * (Kd / 4);
        int blk_w = (int)((total_w + 255) / 256);
        adjust_weight<<<blk_w, 256, 0, stream>>>(W, lA, lB, wb, N, Kd, r);

        int grid = (int)(M / BM) * (N / BN);
        gemm_3phase<<<grid, 512, 0, stream>>>(xb, wb, bias, out, (int)M, N, Kd);
    } else {
        // f32 fallback: xa = x @ lA^T  (M x r), then naive out
        float* xa = (float*)d_ws;   // needs M*r*4 bytes = 512 KB
        long total_xa = M * (long)r;
        int blk_xa = (int)((total_xa + 255) / 256);
        xa_kernel<<<blk_xa, 256, 0, stream>>>(x, lA, xa, M, Kd, r);
        long total_o = M * (long)N;
        int blk_o = (int)((total_o + 255) / 256);
        naive_out<<<blk_o, 256, 0, stream>>>(x, W, bias, xa, lB, out, M, N, Kd, r);
    }
}

// Round 7
// 321.605 us; speedup vs baseline: 1.0833x; 1.0833x over previous
//
#include <hip/hip_runtime.h>
#include <hip/hip_bf16.h>
#include <stdint.h>

typedef __hip_bfloat16 bf16s;                                    // storage type
typedef __bf16 bf16x8 __attribute__((ext_vector_type(8)));       // MFMA operand
typedef float  floatx4 __attribute__((ext_vector_type(4)));      // MFMA acc

#define BM 256
#define BN 256
#define BK 64

__device__ __forceinline__ void gload_lds16(const void* g, void* l) {
    auto* gp = reinterpret_cast<const __attribute__((address_space(1))) uint32_t*>(
        reinterpret_cast<uintptr_t>(g));
    auto* lp = reinterpret_cast<__attribute__((address_space(3))) uint32_t*>(
        reinterpret_cast<uintptr_t>(l));
    __builtin_amdgcn_global_load_lds(gp, lp, 16, 0, 0);
}

// ---------- x (f32) -> bf16, vectorized ----------
__global__ void cvt_f32_bf16(const float* __restrict__ x, bf16s* __restrict__ y, long n4) {
    long i = (long)blockIdx.x * blockDim.x + threadIdx.x;
    long stride = (long)gridDim.x * blockDim.x;
    for (; i < n4; i += stride) {
        float4 v = ((const float4*)x)[i];
        bf16s tmp[4];
        tmp[0] = __float2bfloat16(v.x);
        tmp[1] = __float2bfloat16(v.y);
        tmp[2] = __float2bfloat16(v.z);
        tmp[3] = __float2bfloat16(v.w);
        *(uint2*)&y[i * 4] = *(uint2*)tmp;
    }
}

// ---------- Wadj = W + lora_B @ lora_A, output bf16 ----------
__global__ void adjust_weight(const float* __restrict__ W, const float* __restrict__ lA,
                              const float* __restrict__ lB, bf16s* __restrict__ Wb,
                              int N, int Kd, int r) {
    long idx = (long)blockIdx.x * blockDim.x + threadIdx.x;
    int kq = Kd >> 2;
    long total = (long)N * kq;
    if (idx >= total) return;
    int n  = (int)(idx / kq);
    int k4 = (int)(idx - (long)n * kq) << 2;
    float4 w = *(const float4*)&W[(size_t)n * Kd + k4];
    float a0 = w.x, a1 = w.y, a2 = w.z, a3 = w.w;
    for (int j = 0; j < r; ++j) {
        float b = lB[n * r + j];
        float4 av = *(const float4*)&lA[(size_t)j * Kd + k4];
        a0 += b * av.x; a1 += b * av.y; a2 += b * av.z; a3 += b * av.w;
    }
    bf16s tmp[4];
    tmp[0] = __float2bfloat16(a0);
    tmp[1] = __float2bfloat16(a1);
    tmp[2] = __float2bfloat16(a2);
    tmp[3] = __float2bfloat16(a3);
    *(uint2*)&Wb[(size_t)n * Kd + k4] = *(uint2*)tmp;
}

// ==========================================================================
// 256x256 tile, BK=64, 8 waves (2M x 4N), 16x16x32 MFMA, ONE barrier/K-tile:
//   boundary: s_waitcnt vmcnt(0) + s_barrier publishes the WHOLE tile t.
//   tile body: issue all 8 staging DMAs for t+1 (max latency slack), read all
//   24 fragments, run 4 MFMA quadrant clusters — NO intra-tile barriers, so
//   the 2 waves/SIMD drift and overlap ds_reads with MFMAs (m114 mechanism).
// Correctness ledger:
//   RAW: readers of buf nb start only after boundary(t->t+1) = vmcnt(0)+bar.
//   WAR: loads(t+1) into nb issue after boundary(t-1->t), by which point all
//        readers of nb (tile t-1) have passed that barrier.
// Staging/read layout byte-identical to r4 (measured 0 bank conflicts):
//   LDS slot s of row l holds source granule s^(l&7); A rows wm-major,
//   B rows wn-major so each staged half is gload_lds-contiguous.
// ==========================================================================
__global__ __launch_bounds__(512, 2)
void gemm_1bar(const bf16s* __restrict__ A,   // [M,K] bf16
               const bf16s* __restrict__ B,   // [N,K] bf16
               const float* __restrict__ bias,
               float* __restrict__ C,         // [M,N] f32
               int M, int N, int K) {
    __shared__ __align__(16) bf16s lds[2][2][BM * BK];   // [dbuf][A=0/B=1]

    const int nbn = N / BN;
    const int nwg = gridDim.x;
    int bid = blockIdx.x;
    int swz = bid;
    if ((nwg & 7) == 0) swz = (bid & 7) * (nwg >> 3) + (bid >> 3);   // XCD swizzle
    const int bm = swz / nbn, bn = swz % nbn;

    const int th   = threadIdx.x;
    const int lane = th & 63;
    const int wid  = th >> 6;
    const int wm = wid >> 2;           // 0..1 -> 128-row slice
    const int wn = wid & 3;            // 0..3 -> 64-col slice
    const int lr = lane & 15;
    const int kg = lane >> 4;          // 16B granule group along K

    const bf16s* gA = A + (size_t)(bm * BM) * K;
    const bf16s* gB = B + (size_t)(bn * BN) * K;
    const int NT = K / BK;

    floatx4 acc[8][4];
#pragma unroll
    for (int m = 0; m < 8; ++m)
#pragma unroll
        for (int n = 0; n < 4; ++n)
            acc[m][n] = (floatx4){0.f, 0.f, 0.f, 0.f};

    const int trow = th >> 3;                       // 0..63 rows per G-load
    const int tgr  = (th & 7) ^ (trow & 7);         // pre-swizzled src granule

    auto stageA = [&](int dbuf, int mh, int k0) {
#pragma unroll
        for (int g = 0; g < 2; ++g) {
            int p = g * 128 + mh * 64 + trow;       // phys A row
            gload_lds16(gA + (size_t)p * K + k0 + tgr * 8,
                        &lds[dbuf][0][(mh * 128 + g * 64) * BK + th * 8]);
        }
    };
    auto stageB = [&](int dbuf, int nh, int k0) {
#pragma unroll
        for (int g = 0; g < 2; ++g) {
            int rest = g * 64 + trow;               // 0..127
            int p = (rest >> 5) * 64 + nh * 32 + (rest & 31);   // phys B row
            gload_lds16(gB + (size_t)p * K + k0 + tgr * 8,
                        &lds[dbuf][1][(nh * 128 + g * 64) * BK + th * 8]);
        }
    };

    // ---- fragment reads (swizzled; identical to r4, measured 0 conflicts) ----
    auto ldA = [&](const bf16s* base, int mh, int mp, int kk) -> bf16x8 {
        int l = mh * 128 + wm * 64 + mp * 16 + lr;
        int c = ((kk << 2) | kg) ^ (lr & 7);
        return *(const bf16x8*)(base + l * BK + c * 8);
    };
    auto ldB = [&](const bf16s* base, int nh, int np, int kk) -> bf16x8 {
        int l = nh * 128 + wn * 32 + np * 16 + lr;
        int c = ((kk << 2) | kg) ^ (lr & 7);
        return *(const bf16x8*)(base + l * BK + c * 8);
    };

    // ---- prologue: stage tile 0, publish it ----
    stageA(0, 0, 0);
    stageB(0, 0, 0);
    stageB(0, 1, 0);
    stageA(0, 1, 0);
    asm volatile("s_waitcnt vmcnt(0)" ::: "memory");
    asm volatile("s_barrier" ::: "memory");

    for (int t = 0; t < NT; ++t) {
        const bf16s* Ab = &lds[t & 1][0][0];
        const bf16s* Bb = &lds[t & 1][1][0];
        const int nb = (t + 1) & 1;

        // ---- issue ALL staging for t+1 first (max latency slack; DMA LDS
        // writes land mid-tile when the port has slack) ----
        if (t + 1 < NT) {
            const int k1 = (t + 1) * BK;
            stageA(nb, 0, k1);
            stageB(nb, 0, k1);
            stageB(nb, 1, k1);
            stageA(nb, 1, k1);
        }

        // ---- read all 24 fragments (compiler schedules lgkmcnt finely) ----
        bf16x8 af[4][2], af2[4][2], b0[2][2], b1[2][2];
#pragma unroll
        for (int mp = 0; mp < 4; ++mp)
#pragma unroll
            for (int kk = 0; kk < 2; ++kk)
                af[mp][kk] = ldA(Ab, 0, mp, kk);
#pragma unroll
        for (int np = 0; np < 2; ++np)
#pragma unroll
            for (int kk = 0; kk < 2; ++kk)
                b0[np][kk] = ldB(Bb, 0, np, kk);
#pragma unroll
        for (int np = 0; np < 2; ++np)
#pragma unroll
            for (int kk = 0; kk < 2; ++kk)
                b1[np][kk] = ldB(Bb, 1, np, kk);
#pragma unroll
        for (int mp = 0; mp < 4; ++mp)
#pragma unroll
            for (int kk = 0; kk < 2; ++kk)
                af2[mp][kk] = ldA(Ab, 1, mp, kk);

        // ---- 4 MFMA quadrant clusters (64 MFMA), register-reused operands ----
        __builtin_amdgcn_s_setprio(1);
#pragma unroll
        for (int mp = 0; mp < 4; ++mp)
#pragma unroll
            for (int np = 0; np < 2; ++np)
#pragma unroll
                for (int kk = 0; kk < 2; ++kk)
                    acc[mp][np] = __builtin_amdgcn_mfma_f32_16x16x32_bf16(
                        af[mp][kk], b0[np][kk], acc[mp][np], 0, 0, 0);
#pragma unroll
        for (int mp = 0; mp < 4; ++mp)
#pragma unroll
            for (int np = 0; np < 2; ++np)
#pragma unroll
                for (int kk = 0; kk < 2; ++kk)
                    acc[mp][2 + np] = __builtin_amdgcn_mfma_f32_16x16x32_bf16(
                        af[mp][kk], b1[np][kk], acc[mp][2 + np], 0, 0, 0);
#pragma unroll
        for (int mp = 0; mp < 4; ++mp)
#pragma unroll
            for (int np = 0; np < 2; ++np)
#pragma unroll
                for (int kk = 0; kk < 2; ++kk)
                    acc[4 + mp][2 + np] = __builtin_amdgcn_mfma_f32_16x16x32_bf16(
                        af2[mp][kk], b1[np][kk], acc[4 + mp][2 + np], 0, 0, 0);
#pragma unroll
        for (int mp = 0; mp < 4; ++mp)
#pragma unroll
            for (int np = 0; np < 2; ++np)
#pragma unroll
                for (int kk = 0; kk < 2; ++kk)
                    acc[4 + mp][np] = __builtin_amdgcn_mfma_f32_16x16x32_bf16(
                        af2[mp][kk], b0[np][kk], acc[4 + mp][np], 0, 0, 0);
        __builtin_amdgcn_s_setprio(0);

        // ---- boundary: publish tile t+1 (loads issued ~full tile ago) ----
        asm volatile("s_waitcnt vmcnt(0)" ::: "memory");
        asm volatile("s_barrier" ::: "memory");
    }

    // ---- epilogue: C/D layout col = lane&15, row = (lane>>4)*4 + q ----
    const int crow = bm * BM + wm * 128;
    const int ccol = bn * BN + wn * 64;
#pragma unroll
    for (int n = 0; n < 4; ++n) {
        int col = ccol + n * 16 + lr;
        float bv = bias[col];
#pragma unroll
        for (int m = 0; m < 8; ++m) {
            int row0 = crow + m * 16 + kg * 4;
#pragma unroll
            for (int q = 0; q < 4; ++q)
                C[(size_t)(row0 + q) * N + col] = acc[m][n][q] + bv;
        }
    }
}

// ---------- fallback (f32, slow but correct) ----------
__global__ void xa_kernel(const float* __restrict__ x, const float* __restrict__ lA,
                          float* __restrict__ xa, long M, int K, int r) {
    long idx = (long)blockIdx.x * blockDim.x + threadIdx.x;
    long total = M * r;
    if (idx >= total) return;
    long m = idx / r; int j = (int)(idx % r);
    const float* xr = x + m * (long)K;
    const float* ar = lA + (size_t)j * K;
    float s = 0.f;
    for (int k = 0; k < K; k += 4) {
        float4 xv = *(const float4*)&xr[k];
        float4 av = *(const float4*)&ar[k];
        s += xv.x * av.x + xv.y * av.y + xv.z * av.z + xv.w * av.w;
    }
    xa[idx] = s;
}

__global__ void naive_out(const float* __restrict__ x, const float* __restrict__ W,
                          const float* __restrict__ bias, const float* __restrict__ xa,
                          const float* __restrict__ lB, float* __restrict__ out,
                          long M, int N, int K, int r) {
    long idx = (long)blockIdx.x * blockDim.x + threadIdx.x;
    long total = M * (long)N;
    if (idx >= total) return;
    long m = idx / N; int n = (int)(idx % N);
    const float* xr = x + m * (long)K;
    const float* wr = W + (size_t)n * K;
    float s = bias[n];
    for (int k = 0; k < K; k += 4) {
        float4 xv = *(const float4*)&xr[k];
        float4 wv = *(const float4*)&wr[k];
        s += xv.x * wv.x + xv.y * wv.y + xv.z * wv.z + xv.w * wv.w;
    }
    const float* xar = xa + m * r;
    const float* br  = lB + (size_t)n * r;
    for (int j = 0; j < r; ++j) s += xar[j] * br[j];
    out[idx] = s;
}

extern "C" void kernel_launch(void* const* d_in, const int* in_sizes, int n_in,
                              void* d_out, int out_size, void* d_ws, size_t ws_size,
                              hipStream_t stream) {
    const float* x    = (const float*)d_in[0];
    const float* W    = (const float*)d_in[1];
    const float* bias = (const float*)d_in[2];
    const float* lA   = (const float*)d_in[3];
    const float* lB   = (const float*)d_in[4];
    float* out = (float*)d_out;

    const int  N  = in_sizes[2];                  // d_out = 4096
    const int  Kd = in_sizes[1] / N;              // d_in  = 4096
    const int  r  = in_sizes[4] / N;              // 16
    const long M  = (long)in_sizes[0] / Kd;       // B*S   = 8192

    size_t xb_bytes = (size_t)M * Kd * sizeof(bf16s);
    size_t wb_bytes = (size_t)N * Kd * sizeof(bf16s);

    if (ws_size >= xb_bytes + wb_bytes &&
        (M % BM) == 0 && (N % BN) == 0 && (Kd % BK) == 0) {
        bf16s* xb = (bf16s*)d_ws;
        bf16s* wb = (bf16s*)((char*)d_ws + xb_bytes);

        long n4 = (long)M * Kd / 4;
        cvt_f32_bf16<<<2048, 256, 0, stream>>>(x, xb, n4);

        long total_w = (long)N * (Kd / 4);
        int blk_w = (int)((total_w + 255) / 256);
        adjust_weight<<<blk_w, 256, 0, stream>>>(W, lA, lB, wb, N, Kd, r);

        int grid = (int)(M / BM) * (N / BN);
        gemm_1bar<<<grid, 512, 0, stream>>>(xb, wb, bias, out, (int)M, N, Kd);
    } else {
        // f32 fallback: xa = x @ lA^T  (M x r), then naive out
        float* xa = (float*)d_ws;   // needs M*r*4 bytes = 512 KB
        long total_xa = M * (long)r;
        int blk_xa = (int)((total_xa + 255) / 256);
        xa_kernel<<<blk_xa, 256, 0, stream>>>(x, lA, xa, M, Kd, r);
        long total_o = M * (long)N;
        int blk_o = (int)((total_o + 255) / 256);
        naive_out<<<blk_o, 256, 0, stream>>>(x, W, bias, xa, lB, out, M, N, Kd, r);
    }
}